// Round 7
// baseline (575.200 us; speedup 1.0000x reference)
//
#include <hip/hip_runtime.h>

typedef unsigned short u16;
typedef __attribute__((ext_vector_type(8))) short short8;   // 8 x bf16 (4 VGPRs)
typedef __attribute__((ext_vector_type(4))) float f32x4;    // MFMA C/D frag

#define DEVI __device__ __forceinline__

DEVI float u2f(u16 u) {
    unsigned int x = ((unsigned int)u) << 16;
    float f; __builtin_memcpy(&f, &x, 4); return f;
}
DEVI u16 f2u(float f) {  // RNE bf16 (finite values)
    unsigned int x; __builtin_memcpy(&x, &f, 4);
    x = (x + 0x7fffu + ((x >> 16) & 1u)) >> 16;
    return (u16)x;
}
DEVI unsigned int fbits(float f) {
    unsigned int x; __builtin_memcpy(&x, &f, 4); return x;
}
// async global->LDS, 16B per lane; lds base must be wave-uniform (m104/m108)
DEVI void gld16(const u16* g, u16* ldsbase) {
    __builtin_amdgcn_global_load_lds(
        (const __attribute__((address_space(1))) unsigned int*)g,
        (__attribute__((address_space(3))) unsigned int*)ldsbase, 16, 0, 0);
}

// ---------------------------------------------------------------------------
// Prep (one launch): blocks 0..4095 convert x fp32->bf16 (8 floats/thread);
// blocks 4096..6655 transpose the four weight matrices to K-inner bf16.
// grid 6656, block 256.
__global__ __launch_bounds__(256) void prep(
    const float* __restrict__ x,
    const float* __restrict__ Wq, const float* __restrict__ Wk,
    const float* __restrict__ Wv, const float* __restrict__ Wo,
    u16* __restrict__ xbf, u16* __restrict__ WTqkv, u16* __restrict__ WoT)
{
    __shared__ u16 T[64 * 72];
    int id = blockIdx.x;
    const int tid = threadIdx.x;
    if (id < 4096) {
        int g = (id * 256 + tid) * 8;
        float4 a = *(const float4*)&x[g];
        float4 c = *(const float4*)&x[g + 4];
        short8 v;
        v[0]=(short)f2u(a.x); v[1]=(short)f2u(a.y); v[2]=(short)f2u(a.z); v[3]=(short)f2u(a.w);
        v[4]=(short)f2u(c.x); v[5]=(short)f2u(c.y); v[6]=(short)f2u(c.z); v[7]=(short)f2u(c.w);
        *(short8*)&xbf[g] = v;
        return;
    }
    id -= 4096;
    const float* W; u16* WT; int N, bx, by;
    if (id < 1024)      {            W = Wo; WT = WoT;   N = 2048; bx = id & 31; by = id >> 5; }
    else if (id < 2048) { id -= 1024; W = Wq; WT = WTqkv; N = 2048; bx = id & 31; by = id >> 5; }
    else if (id < 2304) { id -= 2048; W = Wk; WT = WTqkv + (size_t)2048 * 2048; N = 512; bx = id & 7; by = id >> 3; }
    else                { id -= 2304; W = Wv; WT = WTqkv + (size_t)2560 * 2048; N = 512; bx = id & 7; by = id >> 3; }
    const int K = 2048;
    const int k0 = by * 64, n0 = bx * 64;
#pragma unroll
    for (int i = 0; i < 2; ++i) {
        int c = tid + i * 256;              // 0..511
        int row = c >> 3, n8 = (c & 7) * 8;
        const float* src = &W[(size_t)(k0 + row) * N + n0 + n8];
#pragma unroll
        for (int j = 0; j < 8; ++j)
            T[(n8 + j) * 72 + row] = f2u(src[j]);
    }
    __syncthreads();
#pragma unroll
    for (int i = 0; i < 2; ++i) {
        int c = tid + i * 256;
        int n = c >> 3, k8 = (c & 7) * 8;
        *(short8*)&WT[(size_t)(n0 + n) * K + k0 + k8] = *(const short8*)&T[n * 72 + k8];
    }
}

// ---------------------------------------------------------------------------
// GEMM: C[M][N] = A[M][K] @ WT[N][K]^T (+ optional fp32 residual).
// m97 structure: unpadded [128][32] LDS tiles, global_load_lds width=16.
// If fuse_norm: N-tiles with n0<2560 get per-head RMSNorm fused in epilogue.
// C written fp32 if c_f32 else bf16.  grid (N/128, M/128), block 256.
__global__ __launch_bounds__(256) void gemm_lds(
    const u16* __restrict__ A, int lda,
    const u16* __restrict__ WT,
    void* __restrict__ C, int ldc, const float* __restrict__ resid, int c_f32,
    int M, int N, int K,
    const float* __restrict__ qg, const float* __restrict__ kg, int fuse_norm)
{
    __shared__ u16 As[128 * 32];
    __shared__ u16 Bs[128 * 32];
    const int tid = threadIdx.x;
    const int lane = tid & 63, w = tid >> 6;
    const int wm = w >> 1, wn = w & 1;
    const int l15 = lane & 15, quad = lane >> 4;
    const int r4 = lane >> 2, c4 = (lane & 3) * 8;  // DMA: lane->row/col-8
    const int m0 = blockIdx.y * 128, n0 = blockIdx.x * 128;

    f32x4 acc[4][4] = {};
    for (int k0 = 0; k0 < K; k0 += 32) {
#pragma unroll
        for (int j = 0; j < 2; ++j) {
            int row = w * 32 + j * 16;
            gld16(&WT[(size_t)(n0 + row + r4) * K + k0 + c4], &Bs[row * 32]);
            gld16(&A [(size_t)(m0 + row + r4) * lda + k0 + c4], &As[row * 32]);
        }
        __syncthreads();
        short8 a[4], b[4];
#pragma unroll
        for (int mt = 0; mt < 4; ++mt)
            a[mt] = *(const short8*)&As[(wm * 64 + mt * 16 + l15) * 32 + quad * 8];
#pragma unroll
        for (int nt = 0; nt < 4; ++nt)
            b[nt] = *(const short8*)&Bs[(wn * 64 + nt * 16 + l15) * 32 + quad * 8];
#pragma unroll
        for (int mt = 0; mt < 4; ++mt)
#pragma unroll
            for (int nt = 0; nt < 4; ++nt)
                acc[mt][nt] = __builtin_amdgcn_mfma_f32_16x16x32_bf16(a[mt], b[nt], acc[mt][nt], 0, 0, 0);
        __syncthreads();
    }

    if (fuse_norm && n0 < 2560) {
        const float* gamma = (n0 < 2048) ? qg : kg;
        float* red = (float*)As;             // 256 floats, As is dead
#pragma unroll
        for (int mt = 0; mt < 4; ++mt)
#pragma unroll
            for (int r = 0; r < 4; ++r) {
                float p = 0.f;
#pragma unroll
                for (int nt = 0; nt < 4; ++nt) p += acc[mt][nt][r] * acc[mt][nt][r];
#pragma unroll
                for (int msk = 1; msk < 16; msk <<= 1) p += __shfl_xor(p, msk);
                if (l15 == 0)
                    red[(wm * 64 + mt * 16 + quad * 4 + r) * 2 + wn] = p;
            }
        __syncthreads();
        float gv[4];
#pragma unroll
        for (int nt = 0; nt < 4; ++nt) gv[nt] = gamma[wn * 64 + nt * 16 + l15];
#pragma unroll
        for (int mt = 0; mt < 4; ++mt)
#pragma unroll
            for (int r = 0; r < 4; ++r) {
                int rl = wm * 64 + mt * 16 + quad * 4 + r;
                float m2 = red[rl * 2] + red[rl * 2 + 1];
                float sc = rsqrtf(m2 * (1.0f / 128.0f) + 1e-8f);
#pragma unroll
                for (int nt = 0; nt < 4; ++nt) acc[mt][nt][r] *= sc * gv[nt];
            }
    }

#pragma unroll
    for (int mt = 0; mt < 4; ++mt) {
#pragma unroll
        for (int r = 0; r < 4; ++r) {
            int row = m0 + wm * 64 + mt * 16 + quad * 4 + r;
#pragma unroll
            for (int nt = 0; nt < 4; ++nt) {
                int col = n0 + wn * 64 + nt * 16 + l15;
                float v = acc[mt][nt][r];
                if (resid) v += resid[(size_t)row * ldc + col];
                if (c_f32) ((float*)C)[(size_t)row * ldc + col] = v;
                else       ((u16*)C)[(size_t)row * ldc + col] = f2u(v);
            }
        }
    }
}

// ---------------------------------------------------------------------------
// V transpose: vT[(b*4+kvh)*128 + d][s] = qkv[(b*2048+s)][2560 + kvh*128 + d]
// grid (32, 4, 2), block 256.  (bf16)
__global__ __launch_bounds__(256) void vtrans(
    const u16* __restrict__ qkv, u16* __restrict__ vT)
{
    __shared__ u16 T[128 * 72];
    const int tid = threadIdx.x;
    const int t0 = blockIdx.x * 64;
    const int kvh = blockIdx.y, b = blockIdx.z;
#pragma unroll
    for (int i = 0; i < 4; ++i) {
        int c = tid + i * 256;                // 0..1023
        int tl = c >> 4, d8 = (c & 15) * 8;
        short8 v = *(const short8*)&qkv[(size_t)(b * 2048 + t0 + tl) * 3072 + 2560 + kvh * 128 + d8];
#pragma unroll
        for (int j = 0; j < 8; ++j)
            T[(d8 + j) * 72 + tl] = (u16)v[j];
    }
    __syncthreads();
#pragma unroll
    for (int i = 0; i < 4; ++i) {
        int c = tid + i * 256;
        int d = c >> 3, t8 = (c & 7) * 8;
        *(short8*)&vT[((size_t)(b * 4 + kvh) * 128 + d) * 2048 + t0 + t8] =
            *(const short8*)&T[d * 72 + t8];
    }
}

// ---------------------------------------------------------------------------
// Flash attention, causal, GQA, paired q-tiles (qt, 31-qt).  S computed
// TRANSPOSED (mfma(K,Q) => kv=row, q=col) so the P matrix never touches LDS;
// PV A-frags built in-register via v_perm + shuffles.  8 waves/block, waves
// 0-3 own tile qts[0], waves 4-7 own qts[1].
// NEW (round 7): NO LDS AT ALL, NO BARRIERS.  Round 6 proved the limiter is
// a per-CU shared pipe (2x occupancy + half per-wave VALU left dur at
// exactly 107us): the LDS pipe, saturated by 4x-duplicated K/V fragment
// reads (frag addresses depend only on lane, not wave), staging writes,
// bank conflicts (1.09e7/dispatch), and 2 vmcnt(0) barrier drains per iter.
// K/V/Q fragments are now loaded DIRECTLY global->reg at the MFMA sites:
// per-lane 16B loads, 16-lane row groups read contiguous 64B segments;
// K/V tiles (16KB each) are L1/L2-resident and shared across the 8 waves.
// The kv loop is pure {global load, MFMA, softmax VALU, shuffle} — the only
// LDS-pipe users left are the bpermute shuffles.
// grid (16, 16, 2), block 512.
__global__ __launch_bounds__(512) void attn(
    u16* __restrict__ qkv, const u16* __restrict__ vT)
{
    const int tid = threadIdx.x, lane = tid & 63, w = tid >> 6;
    const int t = w >> 2, wq = w & 3;        // tile owner, q-slice in tile
    const int l15 = lane & 15, quad = lane >> 4;
    const int h = blockIdx.y, b = blockIdx.z;
    const int kvh = h >> 2;
    const int qts[2] = { (int)blockIdx.x, 31 - (int)blockIdx.x };
    const int qt = qts[t];                   // this wave's q-tile
    const float scale = 0.08838834764831845f;

    // per-lane operand base pointers
    const u16* const Qg = &qkv[(size_t)(b * 2048 + qt * 64 + wq * 16 + l15) * 3072 + h * 128 + quad * 8];
    const u16* const Kg = &qkv[(size_t)(b * 2048 + l15) * 3072 + 2048 + kvh * 128 + quad * 8];
    const u16* const Vg = &vT[((size_t)(b * 4 + kvh) * 128 + l15) * 2048 + quad * 8];

    // Q fragments: direct global->reg (row = qt*64+wq*16+l15, col = ks*32+quad*8)
    short8 qf[4];
#pragma unroll
    for (int ks = 0; ks < 4; ++ks)
        qf[ks] = *(const short8*)&Qg[ks * 32];

    f32x4 o[8] = {};
    float m_ = -1e30f, l_ = 0.f;

    for (int kt = 0; kt <= qt; ++kt) {       // per-wave bound; no block sync
        const int kv0 = kt * 64;
        // S^T = K Q^T : rows = kv (quad*4+r within 16-tile), cols = q (l15)
        // kf row = kv0 + nt*16 + l15, col = ks*32 + quad*8  (direct load)
        f32x4 s[4];
#pragma unroll
        for (int nt = 0; nt < 4; ++nt) {
            f32x4 a = {};
#pragma unroll
            for (int ks = 0; ks < 4; ++ks) {
                short8 kf = *(const short8*)&Kg[(size_t)(kv0 + nt * 16) * 3072 + ks * 32];
                a = __builtin_amdgcn_mfma_f32_16x16x32_bf16(kf, qf[ks], a, 0, 0, 0);
            }
            s[nt] = a;
        }
        // scale + causal mask (diag tile only); local: kv vs q = wq*16+l15
        if (kt == qt) {
            int qrow = wq * 16 + l15;
#pragma unroll
            for (int nt = 0; nt < 4; ++nt)
#pragma unroll
                for (int r = 0; r < 4; ++r) {
                    float v = s[nt][r] * scale;
                    if (nt * 16 + quad * 4 + r > qrow) v = -1e30f;
                    s[nt][r] = v;
                }
        } else {
#pragma unroll
            for (int nt = 0; nt < 4; ++nt)
#pragma unroll
                for (int r = 0; r < 4; ++r) s[nt][r] *= scale;
        }
        // online softmax, one q-row per lane (q = l15)
        float mx = s[0][0];
#pragma unroll
        for (int nt = 0; nt < 4; ++nt)
#pragma unroll
            for (int r = 0; r < 4; ++r) mx = fmaxf(mx, s[nt][r]);
        mx = fmaxf(mx, __shfl_xor(mx, 16));
        mx = fmaxf(mx, __shfl_xor(mx, 32));
        float mn = fmaxf(m_, mx);
        float alpha = __expf(m_ - mn);
        m_ = mn;
        float sum = 0.f;
#pragma unroll
        for (int nt = 0; nt < 4; ++nt)
#pragma unroll
            for (int r = 0; r < 4; ++r) {
                float p = __expf(s[nt][r] - mn);
                s[nt][r] = p;
                sum += p;
            }
        sum += __shfl_xor(sum, 16);
        sum += __shfl_xor(sum, 32);
        l_ = l_ * alpha + sum;
        // pack P pairs to bf16 (truncate): pk[nt][i] = [p[2i] | p[2i+1]<<16]
        unsigned int pk[4][2];
#pragma unroll
        for (int nt = 0; nt < 4; ++nt)
#pragma unroll
            for (int i = 0; i < 2; ++i)
                pk[nt][i] = __builtin_amdgcn_perm(
                    fbits(s[nt][2 * i + 1]), fbits(s[nt][2 * i]), 0x07060302u);
        // build PV A-frags: lane(l15,quad) chunk c needs kv = 32c+quad*8+j
        int af[2][4];
#pragma unroll
        for (int c = 0; c < 2; ++c)
#pragma unroll
            for (int d = 0; d < 4; ++d) {
                int src = l15 + 16 * ((quad & 1) * 2 + (d >> 1));
                int v0 = __shfl((int)pk[2 * c][d & 1], src);
                int v1 = __shfl((int)pk[2 * c + 1][d & 1], src);
                af[c][d] = (quad >= 2) ? v1 : v0;
            }
        union { int i4[4]; short8 s8; } ua0, ua1;
#pragma unroll
        for (int d = 0; d < 4; ++d) { ua0.i4[d] = af[0][d]; ua1.i4[d] = af[1][d]; }
        // rescale O rows (q = quad*4+r) by alpha broadcast from lane q
#pragma unroll
        for (int r = 0; r < 4; ++r) {
            float ao = __shfl(alpha, quad * 4 + r);
#pragma unroll
            for (int nto = 0; nto < 8; ++nto) o[nto][r] *= ao;
        }
        // O += P V  (bv row d = nto*16+l15, col t = kv0 + {0,32} + quad*8)
#pragma unroll
        for (int nto = 0; nto < 8; ++nto) {
            short8 bv0 = *(const short8*)&Vg[(size_t)(nto * 16) * 2048 + kv0];
            short8 bv1 = *(const short8*)&Vg[(size_t)(nto * 16) * 2048 + kv0 + 32];
            o[nto] = __builtin_amdgcn_mfma_f32_16x16x32_bf16(ua0.s8, bv0, o[nto], 0, 0, 0);
            o[nto] = __builtin_amdgcn_mfma_f32_16x16x32_bf16(ua1.s8, bv1, o[nto], 0, 0, 0);
        }
    }
    // write O in-place over the Q slice (row stride 3072)
    {
        float rl = 1.0f / l_;
#pragma unroll
        for (int r = 0; r < 4; ++r) {
            float inv = __shfl(rl, quad * 4 + r);
            int row = qt * 64 + wq * 16 + quad * 4 + r;
#pragma unroll
            for (int nto = 0; nto < 8; ++nto)
                qkv[(size_t)(b * 2048 + row) * 3072 + h * 128 + nto * 16 + l15] =
                    f2u(o[nto][r] * inv);
        }
    }
}

// ---------------------------------------------------------------------------
// Workspace layout (peak 46.1 MiB, proven):
//   [0,         8388608)  WoT   [2048][2048]   live until final GEMM
//   [8388608,  33554432)  QKV   [4096][3072]   q-slice becomes O in-place
//   [33554432, 37748736)  vT    [8][128][2048] written AFTER WTqkv is dead
//   [33554432, 46137344)  WTqkv [3072][2048]   dead after QKV GEMM
// xbf (bf16 copy of x, 16.8 MB) lives in d_out (dead until final GEMM).
extern "C" void kernel_launch(void* const* d_in, const int* in_sizes, int n_in,
                              void* d_out, int out_size, void* d_ws, size_t ws_size,
                              hipStream_t stream) {
    const float* x  = (const float*)d_in[0];   // [2,2048,2048] fp32
    const float* Wq = (const float*)d_in[1];   // [2048,2048]
    const float* Wk = (const float*)d_in[2];   // [2048,512]
    const float* Wv = (const float*)d_in[3];   // [2048,512]
    const float* Wo = (const float*)d_in[4];   // [2048,2048]
    const float* qg = (const float*)d_in[5];   // [128]
    const float* kg = (const float*)d_in[6];   // [128]

    char* ws = (char*)d_ws;
    u16* WoT   = (u16*)(ws);
    u16* QKV   = (u16*)(ws + 8388608);
    u16* vT    = (u16*)(ws + 33554432);
    u16* WTqkv = (u16*)(ws + 33554432);
    u16* xbf   = (u16*)d_out;                  // 16.8 MB of 33.5 MB; dead at GEMM2

    // 0. x->bf16 + all weight transposes, one launch
    prep<<<dim3(6656), 256, 0, stream>>>(x, Wq, Wk, Wv, Wo, xbf, WTqkv, WoT);

    // 1. QKV projection with fused per-head RMSNorm on q/k tiles
    gemm_lds<<<dim3(24, 32), 256, 0, stream>>>(xbf, 2048, WTqkv, QKV, 3072,
                                               nullptr, 0, 4096, 3072, 2048,
                                               qg, kg, 1);

    // 2. V transpose (WTqkv now dead; vT overlays it)
    vtrans<<<dim3(32, 4, 2), 256, 0, stream>>>(QKV, vT);

    // 3. causal GQA flash attention (paired q-tiles, register-resident P,
    //    LDS-free: direct global->reg operands, zero barriers)
    attn<<<dim3(16, 16, 2), 512, 0, stream>>>(QKV, vT);

    // 4. output projection + residual (C = d_out fp32)
    gemm_lds<<<dim3(16, 32), 256, 0, stream>>>(QKV, 3072, WoT, d_out, 2048,
                                               x, 1, 4096, 2048, 2048,
                                               nullptr, nullptr, 0);
}

// Round 8
// 373.126 us; speedup vs baseline: 1.5416x; 1.5416x over previous
//
#include <hip/hip_runtime.h>

typedef unsigned short u16;
typedef __attribute__((ext_vector_type(8))) short short8;   // 8 x bf16 (4 VGPRs)
typedef __attribute__((ext_vector_type(4))) float f32x4;    // MFMA C/D frag

#define DEVI __device__ __forceinline__

DEVI float u2f(u16 u) {
    unsigned int x = ((unsigned int)u) << 16;
    float f; __builtin_memcpy(&f, &x, 4); return f;
}
DEVI u16 f2u(float f) {  // RNE bf16 (finite values)
    unsigned int x; __builtin_memcpy(&x, &f, 4);
    x = (x + 0x7fffu + ((x >> 16) & 1u)) >> 16;
    return (u16)x;
}
DEVI unsigned int fbits(float f) {
    unsigned int x; __builtin_memcpy(&x, &f, 4); return x;
}
// async global->LDS, 16B per lane; lds base must be wave-uniform (m104/m108)
DEVI void gld16(const u16* g, u16* ldsbase) {
    __builtin_amdgcn_global_load_lds(
        (const __attribute__((address_space(1))) unsigned int*)g,
        (__attribute__((address_space(3))) unsigned int*)ldsbase, 16, 0, 0);
}

// ---------------------------------------------------------------------------
// Prep (one launch): blocks 0..4095 convert x fp32->bf16 (8 floats/thread);
// blocks 4096..6655 transpose the four weight matrices to K-inner bf16.
// grid 6656, block 256.
__global__ __launch_bounds__(256) void prep(
    const float* __restrict__ x,
    const float* __restrict__ Wq, const float* __restrict__ Wk,
    const float* __restrict__ Wv, const float* __restrict__ Wo,
    u16* __restrict__ xbf, u16* __restrict__ WTqkv, u16* __restrict__ WoT)
{
    __shared__ u16 T[64 * 72];
    int id = blockIdx.x;
    const int tid = threadIdx.x;
    if (id < 4096) {
        int g = (id * 256 + tid) * 8;
        float4 a = *(const float4*)&x[g];
        float4 c = *(const float4*)&x[g + 4];
        short8 v;
        v[0]=(short)f2u(a.x); v[1]=(short)f2u(a.y); v[2]=(short)f2u(a.z); v[3]=(short)f2u(a.w);
        v[4]=(short)f2u(c.x); v[5]=(short)f2u(c.y); v[6]=(short)f2u(c.z); v[7]=(short)f2u(c.w);
        *(short8*)&xbf[g] = v;
        return;
    }
    id -= 4096;
    const float* W; u16* WT; int N, bx, by;
    if (id < 1024)      {            W = Wo; WT = WoT;   N = 2048; bx = id & 31; by = id >> 5; }
    else if (id < 2048) { id -= 1024; W = Wq; WT = WTqkv; N = 2048; bx = id & 31; by = id >> 5; }
    else if (id < 2304) { id -= 2048; W = Wk; WT = WTqkv + (size_t)2048 * 2048; N = 512; bx = id & 7; by = id >> 3; }
    else                { id -= 2304; W = Wv; WT = WTqkv + (size_t)2560 * 2048; N = 512; bx = id & 7; by = id >> 3; }
    const int K = 2048;
    const int k0 = by * 64, n0 = bx * 64;
#pragma unroll
    for (int i = 0; i < 2; ++i) {
        int c = tid + i * 256;              // 0..511
        int row = c >> 3, n8 = (c & 7) * 8;
        const float* src = &W[(size_t)(k0 + row) * N + n0 + n8];
#pragma unroll
        for (int j = 0; j < 8; ++j)
            T[(n8 + j) * 72 + row] = f2u(src[j]);
    }
    __syncthreads();
#pragma unroll
    for (int i = 0; i < 2; ++i) {
        int c = tid + i * 256;
        int n = c >> 3, k8 = (c & 7) * 8;
        *(short8*)&WT[(size_t)(n0 + n) * K + k0 + k8] = *(const short8*)&T[n * 72 + k8];
    }
}

// ---------------------------------------------------------------------------
// GEMM: C[M][N] = A[M][K] @ WT[N][K]^T (+ optional fp32 residual).
// m97 structure: unpadded [128][32] LDS tiles, global_load_lds width=16.
// If fuse_norm: N-tiles with n0<2560 get per-head RMSNorm fused in epilogue.
// C written fp32 if c_f32 else bf16.  grid (N/128, M/128), block 256.
__global__ __launch_bounds__(256) void gemm_lds(
    const u16* __restrict__ A, int lda,
    const u16* __restrict__ WT,
    void* __restrict__ C, int ldc, const float* __restrict__ resid, int c_f32,
    int M, int N, int K,
    const float* __restrict__ qg, const float* __restrict__ kg, int fuse_norm)
{
    __shared__ u16 As[128 * 32];
    __shared__ u16 Bs[128 * 32];
    const int tid = threadIdx.x;
    const int lane = tid & 63, w = tid >> 6;
    const int wm = w >> 1, wn = w & 1;
    const int l15 = lane & 15, quad = lane >> 4;
    const int r4 = lane >> 2, c4 = (lane & 3) * 8;  // DMA: lane->row/col-8
    const int m0 = blockIdx.y * 128, n0 = blockIdx.x * 128;

    f32x4 acc[4][4] = {};
    for (int k0 = 0; k0 < K; k0 += 32) {
#pragma unroll
        for (int j = 0; j < 2; ++j) {
            int row = w * 32 + j * 16;
            gld16(&WT[(size_t)(n0 + row + r4) * K + k0 + c4], &Bs[row * 32]);
            gld16(&A [(size_t)(m0 + row + r4) * lda + k0 + c4], &As[row * 32]);
        }
        __syncthreads();
        short8 a[4], b[4];
#pragma unroll
        for (int mt = 0; mt < 4; ++mt)
            a[mt] = *(const short8*)&As[(wm * 64 + mt * 16 + l15) * 32 + quad * 8];
#pragma unroll
        for (int nt = 0; nt < 4; ++nt)
            b[nt] = *(const short8*)&Bs[(wn * 64 + nt * 16 + l15) * 32 + quad * 8];
#pragma unroll
        for (int mt = 0; mt < 4; ++mt)
#pragma unroll
            for (int nt = 0; nt < 4; ++nt)
                acc[mt][nt] = __builtin_amdgcn_mfma_f32_16x16x32_bf16(a[mt], b[nt], acc[mt][nt], 0, 0, 0);
        __syncthreads();
    }

    if (fuse_norm && n0 < 2560) {
        const float* gamma = (n0 < 2048) ? qg : kg;
        float* red = (float*)As;             // 256 floats, As is dead
#pragma unroll
        for (int mt = 0; mt < 4; ++mt)
#pragma unroll
            for (int r = 0; r < 4; ++r) {
                float p = 0.f;
#pragma unroll
                for (int nt = 0; nt < 4; ++nt) p += acc[mt][nt][r] * acc[mt][nt][r];
#pragma unroll
                for (int msk = 1; msk < 16; msk <<= 1) p += __shfl_xor(p, msk);
                if (l15 == 0)
                    red[(wm * 64 + mt * 16 + quad * 4 + r) * 2 + wn] = p;
            }
        __syncthreads();
        float gv[4];
#pragma unroll
        for (int nt = 0; nt < 4; ++nt) gv[nt] = gamma[wn * 64 + nt * 16 + l15];
#pragma unroll
        for (int mt = 0; mt < 4; ++mt)
#pragma unroll
            for (int r = 0; r < 4; ++r) {
                int rl = wm * 64 + mt * 16 + quad * 4 + r;
                float m2 = red[rl * 2] + red[rl * 2 + 1];
                float sc = rsqrtf(m2 * (1.0f / 128.0f) + 1e-8f);
#pragma unroll
                for (int nt = 0; nt < 4; ++nt) acc[mt][nt][r] *= sc * gv[nt];
            }
    }

#pragma unroll
    for (int mt = 0; mt < 4; ++mt) {
#pragma unroll
        for (int r = 0; r < 4; ++r) {
            int row = m0 + wm * 64 + mt * 16 + quad * 4 + r;
#pragma unroll
            for (int nt = 0; nt < 4; ++nt) {
                int col = n0 + wn * 64 + nt * 16 + l15;
                float v = acc[mt][nt][r];
                if (resid) v += resid[(size_t)row * ldc + col];
                if (c_f32) ((float*)C)[(size_t)row * ldc + col] = v;
                else       ((u16*)C)[(size_t)row * ldc + col] = f2u(v);
            }
        }
    }
}

// ---------------------------------------------------------------------------
// V transpose: vT[(b*4+kvh)*128 + d][s] = qkv[(b*2048+s)][2560 + kvh*128 + d]
// grid (32, 4, 2), block 256.  (bf16)
__global__ __launch_bounds__(256) void vtrans(
    const u16* __restrict__ qkv, u16* __restrict__ vT)
{
    __shared__ u16 T[128 * 72];
    const int tid = threadIdx.x;
    const int t0 = blockIdx.x * 64;
    const int kvh = blockIdx.y, b = blockIdx.z;
#pragma unroll
    for (int i = 0; i < 4; ++i) {
        int c = tid + i * 256;                // 0..1023
        int tl = c >> 4, d8 = (c & 15) * 8;
        short8 v = *(const short8*)&qkv[(size_t)(b * 2048 + t0 + tl) * 3072 + 2560 + kvh * 128 + d8];
#pragma unroll
        for (int j = 0; j < 8; ++j)
            T[(d8 + j) * 72 + tl] = (u16)v[j];
    }
    __syncthreads();
#pragma unroll
    for (int i = 0; i < 4; ++i) {
        int c = tid + i * 256;
        int d = c >> 3, t8 = (c & 7) * 8;
        *(short8*)&vT[((size_t)(b * 4 + kvh) * 128 + d) * 2048 + t0 + t8] =
            *(const short8*)&T[d * 72 + t8];
    }
}

// ---------------------------------------------------------------------------
// Flash attention, causal, GQA, paired q-tiles (qt, 31-qt).  S computed
// TRANSPOSED (mfma(K,Q) => kv=row, q=col) so P never touches LDS; PV A-frags
// built in-register via v_perm + shuffles.  8 waves/block: waves 0-3 own
// qts[0], waves 4-7 own qts[1] (r6 base, 107us, VGPR 64, occ 35%).
// NEW (round 8, T2): K/V/Q LDS tiles XOR-SWIZZLED, pads dropped.
//   r6's QS=136/VS=72 pads left K reads 2-4-way and V reads/writes ~8-way
//   bank-conflicted (1.09e7 SQ_LDS_BANK_CONFLICT, ~8.7e6 from K/V after
//   subtracting r7's 2.1e6 bpermute floor).  Natural rows (K/Q 256B, V
//   128B) + byte_off = col_off ^ ((row&7)<<4) on BOTH ds_write and ds_read
//   sides (rule #21; legal because staging is reg->ds_write) spread each
//   16-lane row-group across all eight 16B slots -> conflict-free.
//   r7 proved LDS staging is load-bearing (global->reg operands: 312us).
// LDS 32KB (was 35.8KB).  grid (16, 16, 2), block 512.
#define SWZ(row, coloff) ((coloff) ^ (((row) & 7) << 4))
__global__ __launch_bounds__(512) void attn(
    u16* __restrict__ qkv, const u16* __restrict__ vT)
{
    __shared__ u16 lds[16384];               // 32,768 B
    char* const Kb = (char*)lds;             // K: [64] rows x 256B, swizzled
    char* const Vb = (char*)(lds + 8192);    // V: [128] rows x 128B, swizzled
    // Q staging reuses the whole region: Qb[t] = (char*)(lds + t*8192)

    const int tid = threadIdx.x, lane = tid & 63, w = tid >> 6;
    const int t = w >> 2, wq = w & 3;        // tile owner, q-slice in tile
    const int l15 = lane & 15, quad = lane >> 4;
    const int h = blockIdx.y, b = blockIdx.z;
    const int kvh = h >> 2;
    const int qts[2] = { (int)blockIdx.x, 31 - (int)blockIdx.x };
    const int qt = qts[t];                   // this wave's q-tile
    const float scale = 0.08838834764831845f;

    // stage both Q tiles (swizzled), pull fragments to registers
#pragma unroll
    for (int ts = 0; ts < 2; ++ts)
#pragma unroll
        for (int i = 0; i < 2; ++i) {
            int c = tid + i * 512;           // 0..1023
            int r = c >> 4, co = (c & 15) * 16;
            short8 v = *(const short8*)&qkv[(size_t)(b * 2048 + qts[ts] * 64 + r) * 3072 + h * 128 + (c & 15) * 8];
            *(short8*)((char*)lds + ts * 16384 + r * 256 + SWZ(r, co)) = v;
        }
    __syncthreads();
    short8 qf[4];
    {
        int row = wq * 16 + l15;
#pragma unroll
        for (int ks = 0; ks < 4; ++ks)
            qf[ks] = *(const short8*)((char*)lds + t * 16384 + row * 256 + SWZ(row, ks * 64 + quad * 16));
    }
    __syncthreads();   // region about to be reused as Ks/Vs

    f32x4 o[8] = {};
    float m_ = -1e30f, l_ = 0.f;

    for (int kt = 0; kt <= qts[1]; ++kt) {
        const int kv0 = kt * 64;
#pragma unroll
        for (int i = 0; i < 2; ++i) {
            int c = tid + i * 512;
            int r = c >> 4, co = (c & 15) * 16;
            short8 v = *(const short8*)&qkv[(size_t)(b * 2048 + kv0 + r) * 3072 + 2048 + kvh * 128 + (c & 15) * 8];
            *(short8*)(Kb + r * 256 + SWZ(r, co)) = v;
        }
#pragma unroll
        for (int i = 0; i < 2; ++i) {
            int c = tid + i * 512;
            int d = c >> 3, co = (c & 7) * 16;
            short8 v = *(const short8*)&vT[((size_t)(b * 4 + kvh) * 128 + d) * 2048 + kv0 + (c & 7) * 8];
            *(short8*)(Vb + d * 128 + SWZ(d, co)) = v;
        }
        __syncthreads();

        if (kt <= qt) {                      // wave-uniform: this tile active
            // S^T = K Q^T : rows = kv (quad*4+r within 16-tile), cols = q (l15)
            f32x4 s[4];
#pragma unroll
            for (int nt = 0; nt < 4; ++nt) {
                f32x4 a = {};
                int row = nt * 16 + l15;
#pragma unroll
                for (int ks = 0; ks < 4; ++ks) {
                    short8 kf = *(const short8*)(Kb + row * 256 + SWZ(row, ks * 64 + quad * 16));
                    a = __builtin_amdgcn_mfma_f32_16x16x32_bf16(kf, qf[ks], a, 0, 0, 0);
                }
                s[nt] = a;
            }
            // scale + causal mask (diag tile only); local: kv vs q = wq*16+l15
            if (kt == qt) {
                int qrow = wq * 16 + l15;
#pragma unroll
                for (int nt = 0; nt < 4; ++nt)
#pragma unroll
                    for (int r = 0; r < 4; ++r) {
                        float v = s[nt][r] * scale;
                        if (nt * 16 + quad * 4 + r > qrow) v = -1e30f;
                        s[nt][r] = v;
                    }
            } else {
#pragma unroll
                for (int nt = 0; nt < 4; ++nt)
#pragma unroll
                    for (int r = 0; r < 4; ++r) s[nt][r] *= scale;
            }
            // online softmax, one q-row per lane (q = l15)
            float mx = s[0][0];
#pragma unroll
            for (int nt = 0; nt < 4; ++nt)
#pragma unroll
                for (int r = 0; r < 4; ++r) mx = fmaxf(mx, s[nt][r]);
            mx = fmaxf(mx, __shfl_xor(mx, 16));
            mx = fmaxf(mx, __shfl_xor(mx, 32));
            float mn = fmaxf(m_, mx);
            float alpha = __expf(m_ - mn);
            m_ = mn;
            float sum = 0.f;
#pragma unroll
            for (int nt = 0; nt < 4; ++nt)
#pragma unroll
                for (int r = 0; r < 4; ++r) {
                    float p = __expf(s[nt][r] - mn);
                    s[nt][r] = p;
                    sum += p;
                }
            sum += __shfl_xor(sum, 16);
            sum += __shfl_xor(sum, 32);
            l_ = l_ * alpha + sum;
            // pack P pairs to bf16 (truncate): pk[nt][i] = [p[2i] | p[2i+1]<<16]
            unsigned int pk[4][2];
#pragma unroll
            for (int nt = 0; nt < 4; ++nt)
#pragma unroll
                for (int i = 0; i < 2; ++i)
                    pk[nt][i] = __builtin_amdgcn_perm(
                        fbits(s[nt][2 * i + 1]), fbits(s[nt][2 * i]), 0x07060302u);
            // build PV A-frags: lane(l15,quad) chunk c needs kv = 32c+quad*8+j
            int af[2][4];
#pragma unroll
            for (int c = 0; c < 2; ++c)
#pragma unroll
                for (int d = 0; d < 4; ++d) {
                    int src = l15 + 16 * ((quad & 1) * 2 + (d >> 1));
                    int v0 = __shfl((int)pk[2 * c][d & 1], src);
                    int v1 = __shfl((int)pk[2 * c + 1][d & 1], src);
                    af[c][d] = (quad >= 2) ? v1 : v0;
                }
            union { int i4[4]; short8 s8; } ua0, ua1;
#pragma unroll
            for (int d = 0; d < 4; ++d) { ua0.i4[d] = af[0][d]; ua1.i4[d] = af[1][d]; }
            // rescale O rows (q = quad*4+r) by alpha broadcast from lane q
#pragma unroll
            for (int r = 0; r < 4; ++r) {
                float ao = __shfl(alpha, quad * 4 + r);
#pragma unroll
                for (int nto = 0; nto < 8; ++nto) o[nto][r] *= ao;
            }
            // O += P V  (V row = nto*16+l15; cols quad*8 and 32+quad*8)
#pragma unroll
            for (int nto = 0; nto < 8; ++nto) {
                int row = nto * 16 + l15;
                const char* vb = Vb + row * 128;
                short8 bv0 = *(const short8*)(vb + SWZ(row, quad * 16));
                short8 bv1 = *(const short8*)(vb + SWZ(row, 64 + quad * 16));
                o[nto] = __builtin_amdgcn_mfma_f32_16x16x32_bf16(ua0.s8, bv0, o[nto], 0, 0, 0);
                o[nto] = __builtin_amdgcn_mfma_f32_16x16x32_bf16(ua1.s8, bv1, o[nto], 0, 0, 0);
            }
        }
        __syncthreads();   // before restaging Ks/Vs
    }
    // write O in-place over the Q slice (row stride 3072)
    {
        float rl = 1.0f / l_;
#pragma unroll
        for (int r = 0; r < 4; ++r) {
            float inv = __shfl(rl, quad * 4 + r);
            int row = qt * 64 + wq * 16 + quad * 4 + r;
#pragma unroll
            for (int nto = 0; nto < 8; ++nto)
                qkv[(size_t)(b * 2048 + row) * 3072 + h * 128 + nto * 16 + l15] =
                    f2u(o[nto][r] * inv);
        }
    }
}

// ---------------------------------------------------------------------------
// Workspace layout (peak 46.1 MiB, proven):
//   [0,         8388608)  WoT   [2048][2048]   live until final GEMM
//   [8388608,  33554432)  QKV   [4096][3072]   q-slice becomes O in-place
//   [33554432, 37748736)  vT    [8][128][2048] written AFTER WTqkv is dead
//   [33554432, 46137344)  WTqkv [3072][2048]   dead after QKV GEMM
// xbf (bf16 copy of x, 16.8 MB) lives in d_out (dead until final GEMM).
extern "C" void kernel_launch(void* const* d_in, const int* in_sizes, int n_in,
                              void* d_out, int out_size, void* d_ws, size_t ws_size,
                              hipStream_t stream) {
    const float* x  = (const float*)d_in[0];   // [2,2048,2048] fp32
    const float* Wq = (const float*)d_in[1];   // [2048,2048]
    const float* Wk = (const float*)d_in[2];   // [2048,512]
    const float* Wv = (const float*)d_in[3];   // [2048,512]
    const float* Wo = (const float*)d_in[4];   // [2048,2048]
    const float* qg = (const float*)d_in[5];   // [128]
    const float* kg = (const float*)d_in[6];   // [128]

    char* ws = (char*)d_ws;
    u16* WoT   = (u16*)(ws);
    u16* QKV   = (u16*)(ws + 8388608);
    u16* vT    = (u16*)(ws + 33554432);
    u16* WTqkv = (u16*)(ws + 33554432);
    u16* xbf   = (u16*)d_out;                  // 16.8 MB of 33.5 MB; dead at GEMM2

    // 0. x->bf16 + all weight transposes, one launch
    prep<<<dim3(6656), 256, 0, stream>>>(x, Wq, Wk, Wv, Wo, xbf, WTqkv, WoT);

    // 1. QKV projection with fused per-head RMSNorm on q/k tiles
    gemm_lds<<<dim3(24, 32), 256, 0, stream>>>(xbf, 2048, WTqkv, QKV, 3072,
                                               nullptr, 0, 4096, 3072, 2048,
                                               qg, kg, 1);

    // 2. V transpose (WTqkv now dead; vT overlays it)
    vtrans<<<dim3(32, 4, 2), 256, 0, stream>>>(QKV, vT);

    // 3. causal GQA flash attention (paired q-tiles, register-resident P,
    //    8-wave parallel tile groups, XOR-swizzled K/V/Q LDS)
    attn<<<dim3(16, 16, 2), 512, 0, stream>>>(QKV, vT);

    // 4. output projection + residual (C = d_out fp32)
    gemm_lds<<<dim3(16, 32), 256, 0, stream>>>(QKV, 3072, WoT, d_out, 2048,
                                               x, 1, 4096, 2048, 2048,
                                               nullptr, nullptr, 0);
}